// Round 1
// baseline (622.206 us; speedup 1.0000x reference)
//
#include <hip/hip_runtime.h>
#include <hip/hip_fp8.h>
#include <cstdint>

typedef float f32x4 __attribute__((ext_vector_type(4)));
typedef long long i64;

static constexpr int Mdim = 8192;
static constexpr int Kdim = 4096;
static constexpr int Ndim = 4096;
static constexpr int BM = 128, BN = 128, BK = 64;
static constexpr int NWG_M = Mdim / BM;    // 64
static constexpr int NWG_N = Ndim / BN;    // 32
static constexpr int NWG = NWG_M * NWG_N;  // 2048 (divisible by 8 -> simple XCD swizzle ok)

// ---------------------------------------------------------------------------
// fp32 -> fp8 e4m3fn (OCP), RNE, satfinite. ROCm's tested conversion; handles
// the subnormal range (weights are ALL e4m3-subnormal: |w| < 2^-6).
// ---------------------------------------------------------------------------
__device__ __forceinline__ uint8_t f32_to_e4m3(float f) {
  return (uint8_t)__hip_cvt_float_to_fp8(f, __HIP_SATFINITE, __HIP_E4M3);
}

// ---------------------------------------------------------------------------
// Quantize: 16 floats / thread (4x float4 in, 1x uint4... 16B fp8 out)
// ---------------------------------------------------------------------------
__global__ __launch_bounds__(256) void quant_fp8_kernel(
    const float* __restrict__ in, uint8_t* __restrict__ out, int n_vec16) {
  const int stride = gridDim.x * blockDim.x;
  for (int i = blockIdx.x * blockDim.x + threadIdx.x; i < n_vec16; i += stride) {
    const float4* src = reinterpret_cast<const float4*>(in) + (size_t)i * 4;
    float4 f0 = src[0], f1 = src[1], f2 = src[2], f3 = src[3];
    const float v[16] = {f0.x, f0.y, f0.z, f0.w, f1.x, f1.y, f1.z, f1.w,
                         f2.x, f2.y, f2.z, f2.w, f3.x, f3.y, f3.z, f3.w};
    union alignas(16) {
      uint32_t u[4];
      uint8_t b[16];
    } r;
#pragma unroll
    for (int j = 0; j < 16; ++j) r.b[j] = f32_to_e4m3(v[j]);
    reinterpret_cast<uint4*>(out)[i] = *reinterpret_cast<const uint4*>(r.u);
  }
}

// ---------------------------------------------------------------------------
// Async global->LDS, 16B per lane. LDS dest is wave-uniform base + lane*16,
// so the LDS layout must be linear in lane order (it is: chunk c -> As+c*16).
// ---------------------------------------------------------------------------
__device__ __forceinline__ void gload_lds16(const uint8_t* g, uint8_t* l) {
  __builtin_amdgcn_global_load_lds(
      (const __attribute__((address_space(1))) void*)g,
      (__attribute__((address_space(3))) void*)l, 16, 0, 0);
}

// ---------------------------------------------------------------------------
// fp8 GEMM, m97/m145 structure: 128x128 tile, BK=64, 4 waves (2x2), each wave
// 64x64 via 4x4 frags of mfma_f32_16x16x32_fp8_fp8. Linear LDS (T2 swizzle is
// null at 2-phase per m230/m233 regime gate). out = acc*scale + bias.
// A = x_fp8 [M][K] row-major, B = w_fp8 [N][K] row-major (B^T GEMM).
// ---------------------------------------------------------------------------
__global__ __launch_bounds__(256) void gemm_fp8_kernel(
    const uint8_t* __restrict__ Aq, const uint8_t* __restrict__ Bq,
    const float* __restrict__ bias, const float* __restrict__ sa,
    const float* __restrict__ sb, float* __restrict__ C) {
  __shared__ alignas(16) uint8_t As[BM * BK];  // 8 KiB
  __shared__ alignas(16) uint8_t Bs[BN * BK];  // 8 KiB

  // XCD-aware bijective swizzle (NWG % 8 == 0)
  int wg = (int)blockIdx.x;
  wg = (wg & 7) * (NWG / 8) + (wg >> 3);
  const int bm0 = (wg / NWG_N) * BM;
  const int bn0 = (wg % NWG_N) * BN;

  const int t = (int)threadIdx.x;
  const int lane = t & 63;
  const int wave = t >> 6;
  const int wm = wave >> 1, wn = wave & 1;

  // Staging: tile is 128 rows x 64 B = 512 chunks of 16 B; 256 threads x 2.
  // chunk c -> row = c>>2, byte col = (c&3)*16 ; LDS linear at As + c*16.
  const int c0 = t, c1 = t + 256;
  const int r0 = c0 >> 2, col0 = (c0 & 3) * 16;
  const int r1 = c1 >> 2, col1 = (c1 & 3) * 16;
  const uint8_t* a0 = Aq + (size_t)(bm0 + r0) * Kdim + col0;
  const uint8_t* a1 = Aq + (size_t)(bm0 + r1) * Kdim + col1;
  const uint8_t* b0 = Bq + (size_t)(bn0 + r0) * Kdim + col0;
  const uint8_t* b1 = Bq + (size_t)(bn0 + r1) * Kdim + col1;
  uint8_t* lA0 = As + c0 * 16;
  uint8_t* lA1 = As + c1 * 16;
  uint8_t* lB0 = Bs + c0 * 16;
  uint8_t* lB1 = Bs + c1 * 16;

  // Fragment addressing: A row = wm*64 + m*16 + (lane&15); per-lane K bytes
  // at kk*32 + (lane>>4)*8 (8 contiguous fp8 per lane).
  const int arow = (wm * 64 + (lane & 15)) * BK;
  const int brow = (wn * 64 + (lane & 15)) * BK;
  const int koff = (lane >> 4) * 8;

  f32x4 acc[4][4] = {};

  for (int kt = 0; kt < Kdim / BK; ++kt) {
    const int kb = kt * BK;
    gload_lds16(a0 + kb, lA0);
    gload_lds16(a1 + kb, lA1);
    gload_lds16(b0 + kb, lB0);
    gload_lds16(b1 + kb, lB1);
    __syncthreads();  // compiler emits vmcnt(0) drain before barrier
#pragma unroll
    for (int kk = 0; kk < BK / 32; ++kk) {
      i64 a[4], b[4];
#pragma unroll
      for (int m = 0; m < 4; ++m)
        a[m] = *reinterpret_cast<const i64*>(&As[arow + m * 16 * BK + kk * 32 + koff]);
#pragma unroll
      for (int n = 0; n < 4; ++n)
        b[n] = *reinterpret_cast<const i64*>(&Bs[brow + n * 16 * BK + kk * 32 + koff]);
#pragma unroll
      for (int m = 0; m < 4; ++m)
#pragma unroll
        for (int n = 0; n < 4; ++n)
          acc[m][n] = __builtin_amdgcn_mfma_f32_16x16x32_fp8_fp8(
              a[m], b[n], acc[m][n], 0, 0, 0);
    }
    __syncthreads();
  }

  // Epilogue: C/D layout col = lane&15, row = (lane>>4)*4 + reg (m89-verified)
  const float scale = sa[0] * sb[0];
  const int orow0 = bm0 + wm * 64 + ((lane >> 4) << 2);
  const int ocol0 = bn0 + wn * 64 + (lane & 15);
#pragma unroll
  for (int n = 0; n < 4; ++n) {
    const int col = ocol0 + n * 16;
    const float bv = bias[col];
#pragma unroll
    for (int m = 0; m < 4; ++m) {
      const int row = orow0 + m * 16;
#pragma unroll
      for (int r = 0; r < 4; ++r)
        C[(size_t)(row + r) * Ndim + col] = acc[m][n][r] * scale + bv;
    }
  }
}

// ---------------------------------------------------------------------------
// Fallback (only if d_ws is too small for the fp8 copies): same GEMM but
// stage fp32->cvt->ds_write in registers.
// ---------------------------------------------------------------------------
__device__ __forceinline__ void stage16_cvt(const float* g, uint8_t* l) {
  const float4* s = reinterpret_cast<const float4*>(g);
  float4 f0 = s[0], f1 = s[1], f2 = s[2], f3 = s[3];
  const float v[16] = {f0.x, f0.y, f0.z, f0.w, f1.x, f1.y, f1.z, f1.w,
                       f2.x, f2.y, f2.z, f2.w, f3.x, f3.y, f3.z, f3.w};
  union alignas(16) {
    uint32_t u[4];
    uint8_t b[16];
  } r;
#pragma unroll
  for (int j = 0; j < 16; ++j) r.b[j] = f32_to_e4m3(v[j]);
  *reinterpret_cast<uint4*>(l) = *reinterpret_cast<const uint4*>(r.u);
}

__global__ __launch_bounds__(256) void gemm_fp8_fused_kernel(
    const float* __restrict__ X, const float* __restrict__ W,
    const float* __restrict__ bias, const float* __restrict__ sa,
    const float* __restrict__ sb, float* __restrict__ C) {
  __shared__ alignas(16) uint8_t As[BM * BK];
  __shared__ alignas(16) uint8_t Bs[BN * BK];

  int wg = (int)blockIdx.x;
  wg = (wg & 7) * (NWG / 8) + (wg >> 3);
  const int bm0 = (wg / NWG_N) * BM;
  const int bn0 = (wg % NWG_N) * BN;

  const int t = (int)threadIdx.x;
  const int lane = t & 63;
  const int wave = t >> 6;
  const int wm = wave >> 1, wn = wave & 1;

  const int c0 = t, c1 = t + 256;
  const int r0 = c0 >> 2, col0 = (c0 & 3) * 16;  // col in elements == bytes(fp8)
  const int r1 = c1 >> 2, col1 = (c1 & 3) * 16;
  const float* xa0 = X + (size_t)(bm0 + r0) * Kdim + col0;
  const float* xa1 = X + (size_t)(bm0 + r1) * Kdim + col1;
  const float* wb0 = W + (size_t)(bn0 + r0) * Kdim + col0;
  const float* wb1 = W + (size_t)(bn0 + r1) * Kdim + col1;

  const int arow = (wm * 64 + (lane & 15)) * BK;
  const int brow = (wn * 64 + (lane & 15)) * BK;
  const int koff = (lane >> 4) * 8;

  f32x4 acc[4][4] = {};

  for (int kt = 0; kt < Kdim / BK; ++kt) {
    const int kb = kt * BK;
    stage16_cvt(xa0 + kb, As + c0 * 16);
    stage16_cvt(xa1 + kb, As + c1 * 16);
    stage16_cvt(wb0 + kb, Bs + c0 * 16);
    stage16_cvt(wb1 + kb, Bs + c1 * 16);
    __syncthreads();
#pragma unroll
    for (int kk = 0; kk < BK / 32; ++kk) {
      i64 a[4], b[4];
#pragma unroll
      for (int m = 0; m < 4; ++m)
        a[m] = *reinterpret_cast<const i64*>(&As[arow + m * 16 * BK + kk * 32 + koff]);
#pragma unroll
      for (int n = 0; n < 4; ++n)
        b[n] = *reinterpret_cast<const i64*>(&Bs[brow + n * 16 * BK + kk * 32 + koff]);
#pragma unroll
      for (int m = 0; m < 4; ++m)
#pragma unroll
        for (int n = 0; n < 4; ++n)
          acc[m][n] = __builtin_amdgcn_mfma_f32_16x16x32_fp8_fp8(
              a[m], b[n], acc[m][n], 0, 0, 0);
    }
    __syncthreads();
  }

  const float scale = sa[0] * sb[0];
  const int orow0 = bm0 + wm * 64 + ((lane >> 4) << 2);
  const int ocol0 = bn0 + wn * 64 + (lane & 15);
#pragma unroll
  for (int n = 0; n < 4; ++n) {
    const int col = ocol0 + n * 16;
    const float bv = bias[col];
#pragma unroll
    for (int m = 0; m < 4; ++m) {
      const int row = orow0 + m * 16;
#pragma unroll
      for (int r = 0; r < 4; ++r)
        C[(size_t)(row + r) * Ndim + col] = acc[m][n][r] * scale + bv;
    }
  }
}

// ---------------------------------------------------------------------------
extern "C" void kernel_launch(void* const* d_in, const int* in_sizes, int n_in,
                              void* d_out, int out_size, void* d_ws, size_t ws_size,
                              hipStream_t stream) {
  const float* x = (const float*)d_in[0];      // [M, K]
  const float* w = (const float*)d_in[1];      // [N, K]
  const float* bias = (const float*)d_in[2];   // [N]
  const float* s_in = (const float*)d_in[3];   // scalar
  const float* s_w = (const float*)d_in[4];    // scalar
  float* out = (float*)d_out;                  // [M, N] fp32

  const size_t needA = (size_t)Mdim * Kdim;  // 32 MiB
  const size_t needB = (size_t)Ndim * Kdim;  // 16 MiB

  if (ws_size >= needA + needB) {
    uint8_t* Aq = (uint8_t*)d_ws;
    uint8_t* Bq = Aq + needA;
    quant_fp8_kernel<<<2048, 256, 0, stream>>>(x, Aq, (int)(needA / 16));
    quant_fp8_kernel<<<2048, 256, 0, stream>>>(w, Bq, (int)(needB / 16));
    gemm_fp8_kernel<<<NWG, 256, 0, stream>>>(Aq, Bq, bias, s_in, s_w, out);
  } else {
    gemm_fp8_fused_kernel<<<NWG, 256, 0, stream>>>(x, w, bias, s_in, s_w, out);
  }
}

// Round 2
// 204.565 us; speedup vs baseline: 3.0416x; 3.0416x over previous
//
#include <hip/hip_runtime.h>
#include <hip/hip_fp8.h>
#include <cstdint>

typedef float f32x4 __attribute__((ext_vector_type(4)));
typedef int i32x8 __attribute__((ext_vector_type(8)));
typedef long long i64;

static constexpr int Mdim = 8192;
static constexpr int Kdim = 4096;
static constexpr int Ndim = 4096;
static constexpr int BM = 128, BN = 128, BK = 128;  // BK in fp8 elements == bytes
static constexpr int NWG_M = Mdim / BM;    // 64
static constexpr int NWG_N = Ndim / BN;    // 32
static constexpr int NWG = NWG_M * NWG_N;  // 2048 (divisible by 8)

// ---------------------------------------------------------------------------
// fp32 -> fp8 e4m3fn (OCP), RNE, satfinite.
// ---------------------------------------------------------------------------
__device__ __forceinline__ uint8_t f32_to_e4m3(float f) {
  return (uint8_t)__hip_cvt_float_to_fp8(f, __HIP_SATFINITE, __HIP_E4M3);
}

// ---------------------------------------------------------------------------
// Quantize: 16 floats / thread
// ---------------------------------------------------------------------------
__global__ __launch_bounds__(256) void quant_fp8_kernel(
    const float* __restrict__ in, uint8_t* __restrict__ out, int n_vec16) {
  const int stride = gridDim.x * blockDim.x;
  for (int i = blockIdx.x * blockDim.x + threadIdx.x; i < n_vec16; i += stride) {
    const float4* src = reinterpret_cast<const float4*>(in) + (size_t)i * 4;
    float4 f0 = src[0], f1 = src[1], f2 = src[2], f3 = src[3];
    const float v[16] = {f0.x, f0.y, f0.z, f0.w, f1.x, f1.y, f1.z, f1.w,
                         f2.x, f2.y, f2.z, f2.w, f3.x, f3.y, f3.z, f3.w};
    union alignas(16) {
      uint32_t u[4];
      uint8_t b[16];
    } r;
#pragma unroll
    for (int j = 0; j < 16; ++j) r.b[j] = f32_to_e4m3(v[j]);
    reinterpret_cast<uint4*>(out)[i] = *reinterpret_cast<const uint4*>(r.u);
  }
}

// ---------------------------------------------------------------------------
// Async global->LDS, 16B/lane; LDS dest = wave-uniform base + lane*16.
// ---------------------------------------------------------------------------
__device__ __forceinline__ void gload_lds16(const uint8_t* g, uint8_t* l) {
  __builtin_amdgcn_global_load_lds(
      (const __attribute__((address_space(1))) void*)g,
      (__attribute__((address_space(3))) void*)l, 16, 0, 0);
}

// ---------------------------------------------------------------------------
// MX-fp8 GEMM: 128x128 tile, BK=128, 4 waves (2x2), wave = 64x64 via 4x4
// frags of mfma_scale_f32_16x16x128_f8f6f4 (fp8/fp8, unit e8m0 scales ->
// numerically identical to non-scaled fp8, 2x the rate).
//
// LDS layout: tile[row][col] lives at row*128 + ((col16 ^ (row&7))*16 + col%16
// (16B-granular XOR swizzle). Staging keeps LDS dest LINEAR (global_load_lds
// requirement) and pre-swizzles the GLOBAL source chunk (rule #21: both-sides).
// Read banks: row*128 = 0 mod 32 banks; chunk index kg^(lane&7) is a bijection
// per 8-lane group -> every 8 lanes cover all 32 banks -> 2-way = free (m136).
// ---------------------------------------------------------------------------
__global__ __launch_bounds__(256) void gemm_fp8_mx_kernel(
    const uint8_t* __restrict__ Aq, const uint8_t* __restrict__ Bq,
    const float* __restrict__ bias, const float* __restrict__ sa,
    const float* __restrict__ sb, float* __restrict__ C) {
  __shared__ alignas(16) uint8_t As[BM * BK];  // 16 KiB
  __shared__ alignas(16) uint8_t Bs[BN * BK];  // 16 KiB

  // XCD-aware bijective swizzle (NWG % 8 == 0)
  int wg = (int)blockIdx.x;
  wg = (wg & 7) * (NWG / 8) + (wg >> 3);
  const int bm0 = (wg / NWG_N) * BM;
  const int bn0 = (wg % NWG_N) * BN;

  const int t = (int)threadIdx.x;
  const int lane = t & 63;
  const int wave = t >> 6;
  const int wm = wave >> 1, wn = wave & 1;

  // Staging: tile = 128 rows x 8 chunks(16B) = 1024 chunks; 4 rounds x 256.
  // chunk c = i*256 + t -> row = c>>3 = i*32 + (t>>3), c16 = t&7.
  // LDS dest linear at c*16; global source chunk = c16 ^ (row&7).
  const int srow = t >> 3;                // row within each 32-row group
  const int sc16 = (t & 7) ^ (srow & 7);  // pre-swizzled source chunk
  const uint8_t* aSrc[4];
  const uint8_t* bSrc[4];
#pragma unroll
  for (int i = 0; i < 4; ++i) {
    const int row = i * 32 + srow;        // (row&7) == (srow&7): 32 = 0 mod 8
    aSrc[i] = Aq + (size_t)(bm0 + row) * Kdim + sc16 * 16;
    bSrc[i] = Bq + (size_t)(bn0 + row) * Kdim + sc16 * 16;
  }

  // Fragment reads: lane holds row (lane&15), K bytes [(lane>>4)*32, +32)
  // = chunks kg, kg+1 (kg = (lane>>4)*2), swizzled by XOR (lane&7).
  const int r7 = lane & 7;
  const int kg = (lane >> 4) * 2;
  const int off0 = ((kg ^ r7) * 16);
  const int off1 = (((kg + 1) ^ r7) * 16);
  const int rbA = (wm * 64 + (lane & 15)) * BK;
  const int rbB = (wn * 64 + (lane & 15)) * BK;

  f32x4 acc[4][4] = {};

  for (int kt = 0; kt < Kdim / BK; ++kt) {
    const int kb = kt * BK;
#pragma unroll
    for (int i = 0; i < 4; ++i) {
      gload_lds16(aSrc[i] + kb, As + (i * 256 + t) * 16);
      gload_lds16(bSrc[i] + kb, Bs + (i * 256 + t) * 16);
    }
    __syncthreads();  // vmcnt(0) drain emitted by compiler

    i32x8 af[4], bf[4];
#pragma unroll
    for (int m = 0; m < 4; ++m) {
      const int rb = rbA + m * 16 * BK;
      union {
        i32x8 v;
        int4 h[2];
      } u;
      u.h[0] = *reinterpret_cast<const int4*>(As + rb + off0);
      u.h[1] = *reinterpret_cast<const int4*>(As + rb + off1);
      af[m] = u.v;
    }
#pragma unroll
    for (int n = 0; n < 4; ++n) {
      const int rb = rbB + n * 16 * BK;
      union {
        i32x8 v;
        int4 h[2];
      } u;
      u.h[0] = *reinterpret_cast<const int4*>(Bs + rb + off0);
      u.h[1] = *reinterpret_cast<const int4*>(Bs + rb + off1);
      bf[n] = u.v;
    }

#pragma unroll
    for (int m = 0; m < 4; ++m)
#pragma unroll
      for (int n = 0; n < 4; ++n)
        acc[m][n] = __builtin_amdgcn_mfma_scale_f32_16x16x128_f8f6f4(
            af[m], bf[n], acc[m][n], /*cbsz=fp8*/ 0, /*blgp=fp8*/ 0,
            /*opselA*/ 0, 0x7f7f7f7f, /*opselB*/ 0, 0x7f7f7f7f);
    __syncthreads();
  }

  // Epilogue (C/D: col = lane&15, row = (lane>>4)*4 + reg — round-1-verified)
  const float scale = sa[0] * sb[0];
  const int orow0 = bm0 + wm * 64 + ((lane >> 4) << 2);
  const int ocol0 = bn0 + wn * 64 + (lane & 15);
#pragma unroll
  for (int n = 0; n < 4; ++n) {
    const int col = ocol0 + n * 16;
    const float bv = bias[col];
#pragma unroll
    for (int m = 0; m < 4; ++m) {
      const int row = orow0 + m * 16;
#pragma unroll
      for (int r = 0; r < 4; ++r)
        C[(size_t)(row + r) * Ndim + col] = acc[m][n][r] * scale + bv;
    }
  }
}

// ---------------------------------------------------------------------------
// Fallback (tiny d_ws only): round-1 fused kernel, known-correct.
// ---------------------------------------------------------------------------
__device__ __forceinline__ void stage16_cvt(const float* g, uint8_t* l) {
  const float4* s = reinterpret_cast<const float4*>(g);
  float4 f0 = s[0], f1 = s[1], f2 = s[2], f3 = s[3];
  const float v[16] = {f0.x, f0.y, f0.z, f0.w, f1.x, f1.y, f1.z, f1.w,
                       f2.x, f2.y, f2.z, f2.w, f3.x, f3.y, f3.z, f3.w};
  union alignas(16) {
    uint32_t u[4];
    uint8_t b[16];
  } r;
#pragma unroll
  for (int j = 0; j < 16; ++j) r.b[j] = f32_to_e4m3(v[j]);
  *reinterpret_cast<uint4*>(l) = *reinterpret_cast<const uint4*>(r.u);
}

__global__ __launch_bounds__(256) void gemm_fp8_fused_kernel(
    const float* __restrict__ X, const float* __restrict__ W,
    const float* __restrict__ bias, const float* __restrict__ sa,
    const float* __restrict__ sb, float* __restrict__ C) {
  constexpr int FBK = 64;
  __shared__ alignas(16) uint8_t As[BM * FBK];
  __shared__ alignas(16) uint8_t Bs[BN * FBK];

  int wg = (int)blockIdx.x;
  wg = (wg & 7) * (NWG / 8) + (wg >> 3);
  const int bm0 = (wg / NWG_N) * BM;
  const int bn0 = (wg % NWG_N) * BN;

  const int t = (int)threadIdx.x;
  const int lane = t & 63;
  const int wave = t >> 6;
  const int wm = wave >> 1, wn = wave & 1;

  const int c0 = t, c1 = t + 256;
  const int r0 = c0 >> 2, col0 = (c0 & 3) * 16;
  const int r1 = c1 >> 2, col1 = (c1 & 3) * 16;
  const float* xa0 = X + (size_t)(bm0 + r0) * Kdim + col0;
  const float* xa1 = X + (size_t)(bm0 + r1) * Kdim + col1;
  const float* wb0 = W + (size_t)(bn0 + r0) * Kdim + col0;
  const float* wb1 = W + (size_t)(bn0 + r1) * Kdim + col1;

  const int arow = (wm * 64 + (lane & 15)) * FBK;
  const int brow = (wn * 64 + (lane & 15)) * FBK;
  const int koff = (lane >> 4) * 8;

  f32x4 acc[4][4] = {};

  for (int kt = 0; kt < Kdim / FBK; ++kt) {
    const int kb = kt * FBK;
    stage16_cvt(xa0 + kb, As + c0 * 16);
    stage16_cvt(xa1 + kb, As + c1 * 16);
    stage16_cvt(wb0 + kb, Bs + c0 * 16);
    stage16_cvt(wb1 + kb, Bs + c1 * 16);
    __syncthreads();
#pragma unroll
    for (int kk = 0; kk < FBK / 32; ++kk) {
      i64 a[4], b[4];
#pragma unroll
      for (int m = 0; m < 4; ++m)
        a[m] = *reinterpret_cast<const i64*>(&As[arow + m * 16 * FBK + kk * 32 + koff]);
#pragma unroll
      for (int n = 0; n < 4; ++n)
        b[n] = *reinterpret_cast<const i64*>(&Bs[brow + n * 16 * FBK + kk * 32 + koff]);
#pragma unroll
      for (int m = 0; m < 4; ++m)
#pragma unroll
        for (int n = 0; n < 4; ++n)
          acc[m][n] = __builtin_amdgcn_mfma_f32_16x16x32_fp8_fp8(
              a[m], b[n], acc[m][n], 0, 0, 0);
    }
    __syncthreads();
  }

  const float scale = sa[0] * sb[0];
  const int orow0 = bm0 + wm * 64 + ((lane >> 4) << 2);
  const int ocol0 = bn0 + wn * 64 + (lane & 15);
#pragma unroll
  for (int n = 0; n < 4; ++n) {
    const int col = ocol0 + n * 16;
    const float bv = bias[col];
#pragma unroll
    for (int m = 0; m < 4; ++m) {
      const int row = orow0 + m * 16;
#pragma unroll
      for (int r = 0; r < 4; ++r)
        C[(size_t)(row + r) * Ndim + col] = acc[m][n][r] * scale + bv;
    }
  }
}

// ---------------------------------------------------------------------------
extern "C" void kernel_launch(void* const* d_in, const int* in_sizes, int n_in,
                              void* d_out, int out_size, void* d_ws, size_t ws_size,
                              hipStream_t stream) {
  const float* x = (const float*)d_in[0];      // [M, K]
  const float* w = (const float*)d_in[1];      // [N, K]
  const float* bias = (const float*)d_in[2];   // [N]
  const float* s_in = (const float*)d_in[3];   // scalar
  const float* s_w = (const float*)d_in[4];    // scalar
  float* out = (float*)d_out;                  // [M, N] fp32

  const size_t needA = (size_t)Mdim * Kdim;  // 32 MiB
  const size_t needB = (size_t)Ndim * Kdim;  // 16 MiB

  if (ws_size >= needA + needB) {
    uint8_t* Aq = (uint8_t*)d_ws;
    uint8_t* Bq = Aq + needA;
    quant_fp8_kernel<<<2048, 256, 0, stream>>>(x, Aq, (int)(needA / 16));
    quant_fp8_kernel<<<2048, 256, 0, stream>>>(w, Bq, (int)(needB / 16));
    gemm_fp8_mx_kernel<<<NWG, 256, 0, stream>>>(Aq, Bq, bias, s_in, s_w, out);
  } else {
    gemm_fp8_fused_kernel<<<NWG, 256, 0, stream>>>(x, w, bias, s_in, s_w, out);
  }
}

// Round 3
// 196.871 us; speedup vs baseline: 3.1605x; 1.0391x over previous
//
#include <hip/hip_runtime.h>
#include <hip/hip_fp8.h>
#include <cstdint>

typedef float f32x4 __attribute__((ext_vector_type(4)));
typedef int i32x8 __attribute__((ext_vector_type(8)));
typedef long long i64;

static constexpr int Mdim = 8192;
static constexpr int Kdim = 4096;
static constexpr int Ndim = 4096;

// ---- 256^2 pipelined GEMM geometry ----
static constexpr int BM = 256, BN = 256, BK = 128;  // BK in fp8 bytes
static constexpr int NT = Kdim / BK;                // 32 K-tiles
static constexpr int NWG_M = Mdim / BM;             // 32
static constexpr int NWG_N = Ndim / BN;             // 16
static constexpr int NWG = NWG_M * NWG_N;           // 512 (div by 8)
static_assert(NT >= 4, "pipeline needs >=4 K-tiles");

// ---------------------------------------------------------------------------
// fp32 -> fp8 e4m3fn (OCP), RNE, satfinite.
// ---------------------------------------------------------------------------
__device__ __forceinline__ uint8_t f32_to_e4m3(float f) {
  return (uint8_t)__hip_cvt_float_to_fp8(f, __HIP_SATFINITE, __HIP_E4M3);
}

__global__ __launch_bounds__(256) void quant_fp8_kernel(
    const float* __restrict__ in, uint8_t* __restrict__ out, int n_vec16) {
  const int stride = gridDim.x * blockDim.x;
  for (int i = blockIdx.x * blockDim.x + threadIdx.x; i < n_vec16; i += stride) {
    const float4* src = reinterpret_cast<const float4*>(in) + (size_t)i * 4;
    float4 f0 = src[0], f1 = src[1], f2 = src[2], f3 = src[3];
    const float v[16] = {f0.x, f0.y, f0.z, f0.w, f1.x, f1.y, f1.z, f1.w,
                         f2.x, f2.y, f2.z, f2.w, f3.x, f3.y, f3.z, f3.w};
    union alignas(16) {
      uint32_t u[4];
      uint8_t b[16];
    } r;
#pragma unroll
    for (int j = 0; j < 16; ++j) r.b[j] = f32_to_e4m3(v[j]);
    reinterpret_cast<uint4*>(out)[i] = *reinterpret_cast<const uint4*>(r.u);
  }
}

__device__ __forceinline__ void gload_lds16(const uint8_t* g, uint8_t* l) {
  __builtin_amdgcn_global_load_lds(
      (const __attribute__((address_space(1))) void*)g,
      (__attribute__((address_space(3))) void*)l, 16, 0, 0);
}

__device__ __forceinline__ f32x4 mx_mfma(i32x8 a, i32x8 b, f32x4 c) {
  // fp8 e4m3 A/B, unit e8m0 scales (0x7f) -> identical to non-scaled fp8.
  return __builtin_amdgcn_mfma_scale_f32_16x16x128_f8f6f4(
      a, b, c, 0, 0, 0, 0x7f7f7f7f, 0, 0x7f7f7f7f);
}

// ---------------------------------------------------------------------------
// 256x256 tile, BK=128, 8 waves (2M x 4N), per-wave 128x64 output = 8x4 frags
// of mfma_scale_f32_16x16x128. Prefetch-2 counted-vmcnt pipeline:
//   entry invariant: buf[kt&1] = tile kt complete; tile kt+1's 8 loads in
//   flight. Phase 3: lgkmcnt(0); barrier (all reads of buf[c] done); issue
//   tile kt+2 -> buf[c]; MFMA; vmcnt(8) (tile kt+1 landed, kt+2 in flight);
//   barrier. Raw s_barrier (NOT __syncthreads) keeps loads across barriers.
// LDS 16B-chunk XOR swizzle (round-2-verified): slot s of row r holds global
// chunk s ^ (r&7); gload_lds dest stays linear, SOURCE is pre-swizzled.
// ---------------------------------------------------------------------------
__global__ __launch_bounds__(512, 2) void gemm_fp8_mx_256(
    const uint8_t* __restrict__ Aq, const uint8_t* __restrict__ Bq,
    const float* __restrict__ bias, const float* __restrict__ sa,
    const float* __restrict__ sb, float* __restrict__ C) {
  __shared__ alignas(16) uint8_t sA[2][BM * BK];  // 2 x 32 KiB
  __shared__ alignas(16) uint8_t sB[2][BN * BK];  // 2 x 32 KiB

  int wg = (int)blockIdx.x;
  wg = (wg & 7) * (NWG / 8) + (wg >> 3);  // XCD swizzle (512 % 8 == 0)
  const int bm0 = (wg / NWG_N) * BM;
  const int bn0 = (wg % NWG_N) * BN;

  const int t = (int)threadIdx.x;  // 0..511
  const int lane = t & 63;
  const int wave = t >> 6;   // 0..7
  const int wm = wave >> 2;  // 0..1  -> A rows wm*128..+127
  const int wn = wave & 3;   // 0..3  -> B rows wn*64..+63

  // ---- staging: 512 thr x 16 B = 8 KiB/call; 4 calls per matrix per K-tile.
  // call i, thread t: row = i*64 + (t>>3); source chunk pre-swizzled.
  const int srow = t >> 3;                // 0..63
  const int sc16 = (t & 7) ^ (srow & 7);  // (i*64) % 8 == 0, so row&7 == srow&7
  const uint8_t* aBase = Aq + (size_t)(bm0 + srow) * Kdim + sc16 * 16;
  const uint8_t* bBase = Bq + (size_t)(bn0 + srow) * Kdim + sc16 * 16;
  const int ldsOff = t * 16;

  auto stage = [&](int buf, int kt) {
    const int kb = kt * BK;
#pragma unroll
    for (int i = 0; i < 4; ++i)
      gload_lds16(aBase + kb + (size_t)i * (64 * Kdim),
                  &sA[buf][i * 8192 + ldsOff]);
#pragma unroll
    for (int i = 0; i < 4; ++i)
      gload_lds16(bBase + kb + (size_t)i * (64 * Kdim),
                  &sB[buf][i * 8192 + ldsOff]);
  };

  // ---- fragment reads: lane row = (lane&15), K chunks kg,kg+1 (swizzled)
  const int r7 = lane & 7;
  const int kg = (lane >> 4) * 2;
  const int off0 = (kg ^ r7) * 16;
  const int off1 = ((kg + 1) ^ r7) * 16;
  const int rbA = (wm * 128 + (lane & 15)) * BK;
  const int rbB = (wn * 64 + (lane & 15)) * BK;

  auto ldfrag = [&](const uint8_t* base) -> i32x8 {
    union {
      i32x8 v;
      int4 h[2];
    } u;
    u.h[0] = *reinterpret_cast<const int4*>(base + off0);
    u.h[1] = *reinterpret_cast<const int4*>(base + off1);
    return u.v;
  };

  f32x4 acc[8][4] = {};

  // ---- prologue: tiles 0,1 in flight; wait tile 0 only (counted).
  stage(0, 0);
  stage(1, 1);
  asm volatile("s_waitcnt vmcnt(8)" ::: "memory");
  __builtin_amdgcn_s_barrier();
  asm volatile("" ::: "memory");

#pragma unroll 1
  for (int kt = 0; kt < NT; ++kt) {
    const int c = kt & 1;
    const uint8_t* A = &sA[c][0];
    const uint8_t* B = &sB[c][0];

    // phase 0: all B-frags + A-frags 0,1
    i32x8 bf[4];
#pragma unroll
    for (int n = 0; n < 4; ++n) bf[n] = ldfrag(B + rbB + n * 16 * BK);
    i32x8 a0 = ldfrag(A + rbA + 0 * 16 * BK);
    i32x8 a1 = ldfrag(A + rbA + 1 * 16 * BK);
    __builtin_amdgcn_s_setprio(1);
#pragma unroll
    for (int n = 0; n < 4; ++n) acc[0][n] = mx_mfma(a0, bf[n], acc[0][n]);
#pragma unroll
    for (int n = 0; n < 4; ++n) acc[1][n] = mx_mfma(a1, bf[n], acc[1][n]);
    __builtin_amdgcn_s_setprio(0);

    // phase 1: A-frags 2,3
    a0 = ldfrag(A + rbA + 2 * 16 * BK);
    a1 = ldfrag(A + rbA + 3 * 16 * BK);
    __builtin_amdgcn_s_setprio(1);
#pragma unroll
    for (int n = 0; n < 4; ++n) acc[2][n] = mx_mfma(a0, bf[n], acc[2][n]);
#pragma unroll
    for (int n = 0; n < 4; ++n) acc[3][n] = mx_mfma(a1, bf[n], acc[3][n]);
    __builtin_amdgcn_s_setprio(0);

    // phase 2: A-frags 4,5
    a0 = ldfrag(A + rbA + 4 * 16 * BK);
    a1 = ldfrag(A + rbA + 5 * 16 * BK);
    __builtin_amdgcn_s_setprio(1);
#pragma unroll
    for (int n = 0; n < 4; ++n) acc[4][n] = mx_mfma(a0, bf[n], acc[4][n]);
#pragma unroll
    for (int n = 0; n < 4; ++n) acc[5][n] = mx_mfma(a1, bf[n], acc[5][n]);
    __builtin_amdgcn_s_setprio(0);

    // phase 3: A-frags 6,7; stage tile kt+2 after all-reads-done barrier
    a0 = ldfrag(A + rbA + 6 * 16 * BK);
    a1 = ldfrag(A + rbA + 7 * 16 * BK);
    asm volatile("s_waitcnt lgkmcnt(0)" ::: "memory");  // my buf[c] reads done
    __builtin_amdgcn_s_barrier();                       // everyone's reads done
    asm volatile("" ::: "memory");
    if (kt + 2 < NT) stage(c, kt + 2);  // overwrite buf[c] (now safe)
    __builtin_amdgcn_s_setprio(1);
#pragma unroll
    for (int n = 0; n < 4; ++n) acc[6][n] = mx_mfma(a0, bf[n], acc[6][n]);
#pragma unroll
    for (int n = 0; n < 4; ++n) acc[7][n] = mx_mfma(a1, bf[n], acc[7][n]);
    __builtin_amdgcn_s_setprio(0);

    if (kt + 2 < NT) {
      // tile kt+1's 8 loads are the oldest; kt+2's 8 may stay in flight
      asm volatile("s_waitcnt vmcnt(8)" ::: "memory");
      __builtin_amdgcn_s_barrier();
      asm volatile("" ::: "memory");
    } else if (kt + 1 < NT) {
      asm volatile("s_waitcnt vmcnt(0)" ::: "memory");  // tail drain
      __builtin_amdgcn_s_barrier();
      asm volatile("" ::: "memory");
    }
  }

  // ---- epilogue (C/D: col = lane&15, row = (lane>>4)*4 + reg)
  const float scale = sa[0] * sb[0];
  const int orow0 = bm0 + wm * 128 + ((lane >> 4) << 2);
  const int ocol0 = bn0 + wn * 64 + (lane & 15);
#pragma unroll
  for (int n = 0; n < 4; ++n) {
    const int col = ocol0 + n * 16;
    const float bv = bias[col];
#pragma unroll
    for (int m = 0; m < 8; ++m) {
      const int row = orow0 + m * 16;
#pragma unroll
      for (int r = 0; r < 4; ++r)
        C[(size_t)(row + r) * Ndim + col] = acc[m][n][r] * scale + bv;
    }
  }
}

// ---------------------------------------------------------------------------
// Fallback (tiny d_ws only): round-1 fused kernel, known-correct.
// ---------------------------------------------------------------------------
__device__ __forceinline__ void stage16_cvt(const float* g, uint8_t* l) {
  const float4* s = reinterpret_cast<const float4*>(g);
  float4 f0 = s[0], f1 = s[1], f2 = s[2], f3 = s[3];
  const float v[16] = {f0.x, f0.y, f0.z, f0.w, f1.x, f1.y, f1.z, f1.w,
                       f2.x, f2.y, f2.z, f2.w, f3.x, f3.y, f3.z, f3.w};
  union alignas(16) {
    uint32_t u[4];
    uint8_t b[16];
  } r;
#pragma unroll
  for (int j = 0; j < 16; ++j) r.b[j] = f32_to_e4m3(v[j]);
  *reinterpret_cast<uint4*>(l) = *reinterpret_cast<const uint4*>(r.u);
}

__global__ __launch_bounds__(256) void gemm_fp8_fused_kernel(
    const float* __restrict__ X, const float* __restrict__ W,
    const float* __restrict__ bias, const float* __restrict__ sa,
    const float* __restrict__ sb, float* __restrict__ C) {
  constexpr int FBM = 128, FBN = 128, FBK = 64;
  constexpr int FNWG_N = Ndim / FBN;
  __shared__ alignas(16) uint8_t As[FBM * FBK];
  __shared__ alignas(16) uint8_t Bs[FBN * FBK];

  int wg = (int)blockIdx.x;
  const int nwg = (Mdim / FBM) * FNWG_N;
  wg = (wg & 7) * (nwg / 8) + (wg >> 3);
  const int bm0 = (wg / FNWG_N) * FBM;
  const int bn0 = (wg % FNWG_N) * FBN;

  const int t = (int)threadIdx.x;
  const int lane = t & 63;
  const int wave = t >> 6;
  const int wm = wave >> 1, wn = wave & 1;

  const int c0 = t, c1 = t + 256;
  const int r0 = c0 >> 2, col0 = (c0 & 3) * 16;
  const int r1 = c1 >> 2, col1 = (c1 & 3) * 16;
  const float* xa0 = X + (size_t)(bm0 + r0) * Kdim + col0;
  const float* xa1 = X + (size_t)(bm0 + r1) * Kdim + col1;
  const float* wb0 = W + (size_t)(bn0 + r0) * Kdim + col0;
  const float* wb1 = W + (size_t)(bn0 + r1) * Kdim + col1;

  const int arow = (wm * 64 + (lane & 15)) * FBK;
  const int brow = (wn * 64 + (lane & 15)) * FBK;
  const int koff = (lane >> 4) * 8;

  f32x4 acc[4][4] = {};

  for (int kt = 0; kt < Kdim / FBK; ++kt) {
    const int kb = kt * FBK;
    stage16_cvt(xa0 + kb, As + c0 * 16);
    stage16_cvt(xa1 + kb, As + c1 * 16);
    stage16_cvt(wb0 + kb, Bs + c0 * 16);
    stage16_cvt(wb1 + kb, Bs + c1 * 16);
    __syncthreads();
#pragma unroll
    for (int kk = 0; kk < FBK / 32; ++kk) {
      i64 a[4], b[4];
#pragma unroll
      for (int m = 0; m < 4; ++m)
        a[m] = *reinterpret_cast<const i64*>(&As[arow + m * 16 * FBK + kk * 32 + koff]);
#pragma unroll
      for (int n = 0; n < 4; ++n)
        b[n] = *reinterpret_cast<const i64*>(&Bs[brow + n * 16 * FBK + kk * 32 + koff]);
#pragma unroll
      for (int m = 0; m < 4; ++m)
#pragma unroll
        for (int n = 0; n < 4; ++n)
          acc[m][n] = __builtin_amdgcn_mfma_f32_16x16x32_fp8_fp8(
              a[m], b[n], acc[m][n], 0, 0, 0);
    }
    __syncthreads();
  }

  const float scale = sa[0] * sb[0];
  const int orow0 = bm0 + wm * 64 + ((lane >> 4) << 2);
  const int ocol0 = bn0 + wn * 64 + (lane & 15);
#pragma unroll
  for (int n = 0; n < 4; ++n) {
    const int col = ocol0 + n * 16;
    const float bv = bias[col];
#pragma unroll
    for (int m = 0; m < 4; ++m) {
      const int row = orow0 + m * 16;
#pragma unroll
      for (int r = 0; r < 4; ++r)
        C[(size_t)(row + r) * Ndim + col] = acc[m][n][r] * scale + bv;
    }
  }
}

// ---------------------------------------------------------------------------
extern "C" void kernel_launch(void* const* d_in, const int* in_sizes, int n_in,
                              void* d_out, int out_size, void* d_ws, size_t ws_size,
                              hipStream_t stream) {
  const float* x = (const float*)d_in[0];      // [M, K]
  const float* w = (const float*)d_in[1];      // [N, K]
  const float* bias = (const float*)d_in[2];   // [N]
  const float* s_in = (const float*)d_in[3];   // scalar
  const float* s_w = (const float*)d_in[4];    // scalar
  float* out = (float*)d_out;                  // [M, N] fp32

  const size_t needA = (size_t)Mdim * Kdim;  // 32 MiB
  const size_t needB = (size_t)Ndim * Kdim;  // 16 MiB

  if (ws_size >= needA + needB) {
    uint8_t* Aq = (uint8_t*)d_ws;
    uint8_t* Bq = Aq + needA;
    quant_fp8_kernel<<<2048, 256, 0, stream>>>(x, Aq, (int)(needA / 16));
    quant_fp8_kernel<<<2048, 256, 0, stream>>>(w, Bq, (int)(needB / 16));
    gemm_fp8_mx_256<<<NWG, 512, 0, stream>>>(Aq, Bq, bias, s_in, s_w, out);
  } else {
    gemm_fp8_fused_kernel<<<(Mdim / 128) * (Ndim / 128), 256, 0, stream>>>(
        x, w, bias, s_in, s_w, out);
  }
}